// Round 14
// baseline (219.277 us; speedup 1.0000x reference)
//
#include <hip/hip_runtime.h>
#include <hip/hip_bf16.h>

// GraphSAGE fused kernels for MI355X (gfx950).
// N=768, NODE_IN=64, EDGE_IN=32, H=128, ROUNDS=2.
//
// Round 14: barrier-free streaming k_big. R12's 47us was barrier-lockstep
// (24 barriers x 8 waves; MfmaUtil 20%, HBM 5%). R13's spT layout regressed
// (16B x 3KB-stride gather) -> reverted. Now R5's wave-private structure
// (4 waves, each owns 16-row chunks end-to-end, private E region, ZERO
// main-loop barriers) combined with R12's streaming efT (the gather ceiling
// fix). Wa2 served from the swizzled 32KB LDS copy (conflict-free b128).
// LDS 52KB -> exactly 3 blocks/CU = full co-residency of the 768-block grid.

typedef __bf16 bf16x8 __attribute__((ext_vector_type(8)));
typedef float f32x4 __attribute__((ext_vector_type(4)));

#define NN 768

static __device__ __forceinline__ unsigned short to_bf16u(float x) {
    return __builtin_bit_cast(unsigned short, (__bf16)x);
}

// ---------------------------------------------------------------- fused prep
// blocks 0..2303   : ef[i][j][f] fp32 -> efT[j][i][f] bf16 (LDS-tiled)
// blocks 2304..2879: adj transpose (32x32 tiles)
// blocks 2880..2959: weight transposes We->WeT, Wa[H:]->Wa2T (bf16 k-minor)
// blocks 2960..3343: h0 = relu(nf@Wn+bn) and sp = h0@Wa[:H]+ba (plain layout)
__global__ __launch_bounds__(256) void k_prep(
                       const float* __restrict__ ef, unsigned short* __restrict__ efT,
                       const float* __restrict__ adj, float* __restrict__ adjT,
                       const float* __restrict__ We, const float* __restrict__ Wa,
                       unsigned short* __restrict__ WeT, unsigned short* __restrict__ Wa2T,
                       const float* __restrict__ nf, const float* __restrict__ Wn,
                       const float* __restrict__ bn, const float* __restrict__ ba,
                       float* __restrict__ h, float* __restrict__ sp) {
    const int b = blockIdx.x, tid = threadIdx.x;
    if (b < 2304) {
        __shared__ unsigned short tile[8 * 1288 + 8];  // plane 1288, row 40
        const int i0 = (b % 24) * 32, j0 = (b / 24) * 8;
        {
            const int jj = tid >> 5, ff = tid & 31;
#pragma unroll 4
            for (int i = 0; i < 32; ++i) {
                float v = ef[((size_t)(i0 + i) * NN + j0 + jj) * 32 + ff];
                tile[jj * 1288 + i * 40 + ff] = to_bf16u(v);
            }
        }
        __syncthreads();
        const int tp = tid & 31, j = tid >> 5;
        unsigned short* dst = efT + ((size_t)(j0 + j) * NN + i0) * 32;
#pragma unroll
        for (int v = 0; v < 4; ++v) {
            int flat = v * 256 + tp * 8;
            int i = flat >> 5, f = flat & 31;
            bf16x8 val = *reinterpret_cast<const bf16x8*>(&tile[j * 1288 + i * 40 + f]);
            *reinterpret_cast<bf16x8*>(dst + flat) = val;
        }
    } else if (b < 2880) {
        __shared__ float tile[32][33];
        int bb = b - 2304;
        int bx = bb % 24, by = bb / 24;
        int tx = tid & 31, ty = tid >> 5;  // 32 x 8
#pragma unroll
        for (int yy = 0; yy < 32; yy += 8)
            tile[ty + yy][tx] = adj[(size_t)(by * 32 + ty + yy) * NN + bx * 32 + tx];
        __syncthreads();
#pragma unroll
        for (int yy = 0; yy < 32; yy += 8)
            adjT[(size_t)(bx * 32 + ty + yy) * NN + by * 32 + tx] = tile[tx][ty + yy];
    } else if (b < 2960) {
        int g = (b - 2880) * 256 + tid;
        if (g < 128 * 32) {
            int c = g >> 5, f = g & 31;
            WeT[g] = to_bf16u(We[f * 128 + c]);
        } else {
            int g2 = g - 128 * 32;
            int c = g2 >> 7, k = g2 & 127;
            Wa2T[g2] = to_bf16u(Wa[(128 + k) * 128 + c]);
        }
    } else {
        __shared__ float nf_l[2][64];
        __shared__ float h_l[2][128];
        int row = tid >> 7, t = tid & 127;
        int i = (b - 2960) * 2 + row;
        if (t < 64) nf_l[row][t] = nf[i * 64 + t];
        __syncthreads();
        float acc = bn[t];
#pragma unroll 8
        for (int f = 0; f < 64; ++f) acc += nf_l[row][f] * Wn[f * 128 + t];
        acc = fmaxf(acc, 0.f);
        h[i * 128 + t] = acc;
        h_l[row][t] = acc;
        __syncthreads();
        float spv = ba[t];
#pragma unroll 8
        for (int f = 0; f < 128; ++f) spv += h_l[row][f] * Wa[f * 128 + t];
        sp[i * 128 + t] = spv;
    }
}

// ---------------------------------------------------------------- barrier-free streaming k_big
// Block = receiver j. 4 waves; wave w owns rows [192w, 192w+192) in 12
// sequential 16-row chunks, fully private pipeline (global A-frag -> GEMM1
// -> private LDS E -> GEMM2 -> masked accumulate). No main-loop barriers.
__global__ __launch_bounds__(256) void k_big_s(
    const unsigned short* __restrict__ efT, const float* __restrict__ adjT,
    const float* __restrict__ sp, const unsigned short* __restrict__ WeT,
    const unsigned short* __restrict__ Wa2T, const float* __restrict__ be,
    float* __restrict__ agg) {
    __shared__ unsigned short wa2_lds[128 * 128];               // 32KB, XOR-swizzled
    __shared__ __align__(16) unsigned short e_lds[4][16 * 128]; // 4KB per wave
    __shared__ float adj_lds[NN];
    __shared__ float wred[4];
    __shared__ float s_invdeg;

    const int tid  = threadIdx.x;
    const int j    = blockIdx.x;
    const int lane = tid & 63;
    const int wv   = tid >> 6;
    const int lg   = lane >> 4;
    const int lr   = lane & 15;

    // ---- stage Wa2T -> swizzled LDS
    {
        const int col = tid >> 1;
        const int kb  = (tid & 1) * 64;
#pragma unroll
        for (int m = 0; m < 8; ++m) {
            bf16x8 v = *reinterpret_cast<const bf16x8*>(Wa2T + col * 128 + kb + 8 * m);
            int idx = (col * 128 + kb + 8 * m) ^ ((col & 7) << 3);
            *reinterpret_cast<bf16x8*>(&wa2_lds[idx]) = v;
        }
    }
    // ---- adj column j (coalesced) + degree
    float asum = 0.f;
    for (int k = tid; k < NN; k += 256) {
        float a = adjT[(size_t)j * NN + k];
        adj_lds[k] = a;
        asum += a;
    }
#pragma unroll
    for (int off = 32; off; off >>= 1) asum += __shfl_down(asum, off);
    if (lane == 0) wred[wv] = asum;

    // ---- GEMM1 B-frags (We) + be in regs
    bf16x8 bwe[8];
    float bereg[8];
#pragma unroll
    for (int t = 0; t < 8; ++t) {
        int col = 16 * t + lr;
        bwe[t] = *reinterpret_cast<const bf16x8*>(WeT + col * 32 + 8 * lg);
        bereg[t] = be[col];
    }
    __syncthreads();
    if (tid == 0) s_invdeg = 1.0f / fmaxf(wred[0] + wred[1] + wred[2] + wred[3], 1.0f);

    float aggp[8] = {0.f, 0.f, 0.f, 0.f, 0.f, 0.f, 0.f, 0.f};

    const int rowbase = 192 * wv;
    // streaming load: wave covers 16 consecutive rows = contiguous 1KB
    auto load_ef = [&](int c, bf16x8& x) {
        int row = rowbase + 16 * c + lr;
        x = *reinterpret_cast<const bf16x8*>(efT + ((size_t)j * NN + row) * 32 + 8 * lg);
    };

    bf16x8 cA;
    load_ef(0, cA);

    for (int c = 0; c < 12; ++c) {
        bf16x8 pA;
        if (c + 1 < 12) load_ef(c + 1, pA);

        // ---- GEMM1: E(16x128) = relu(EF @ We + be) -> private swizzled LDS
#pragma unroll
        for (int t = 0; t < 8; ++t) {
            f32x4 cc;
            cc[0] = bereg[t]; cc[1] = bereg[t]; cc[2] = bereg[t]; cc[3] = bereg[t];
            f32x4 C1 = __builtin_amdgcn_mfma_f32_16x16x32_bf16(cA, bwe[t], cc, 0, 0, 0);
#pragma unroll
            for (int r = 0; r < 4; ++r) {
                int row = 4 * lg + r, col = 16 * t + lr;
                int idx = (row * 128 + col) ^ ((row & 7) << 3);
                e_lds[wv][idx] = to_bf16u(fmaxf(C1[r], 0.f));
            }
        }
        // ---- GEMM2 A-frags (wave-synchronous LDS round trip)
        bf16x8 ae[4];
#pragma unroll
        for (int s = 0; s < 4; ++s) {
            int idx = (lr * 128 + 32 * s + 8 * lg) ^ ((lr & 7) << 3);
            ae[s] = *reinterpret_cast<const bf16x8*>(&e_lds[wv][idx]);
        }
        const int i0 = rowbase + 16 * c + 4 * lg;
        f32x4 av = *reinterpret_cast<const f32x4*>(&adj_lds[i0]);
        // ---- GEMM2: P = E @ Wa2 + sp, relu, mask, accumulate
#pragma unroll
        for (int t = 0; t < 8; ++t) {
            const int col = 16 * t + lr;
            f32x4 acc;
#pragma unroll
            for (int r = 0; r < 4; ++r)
                acc[r] = sp[(size_t)(i0 + r) * 128 + col];
#pragma unroll
            for (int s = 0; s < 4; ++s) {
                int widx = (col * 128 + 32 * s + 8 * lg) ^ ((col & 7) << 3);
                bf16x8 bw = *reinterpret_cast<const bf16x8*>(&wa2_lds[widx]);
                acc = __builtin_amdgcn_mfma_f32_16x16x32_bf16(ae[s], bw, acc, 0, 0, 0);
            }
#pragma unroll
            for (int r = 0; r < 4; ++r)
                aggp[t] += fmaxf(acc[r], 0.f) * av[r];
        }

        if (c + 1 < 12) cA = pA;
    }

    // ---- reduce: shfl over lg groups within wave, then across waves
    float* redw = reinterpret_cast<float*>(&e_lds[wv][0]);
    __syncthreads();   // all waves done with E regions before reuse
#pragma unroll
    for (int t = 0; t < 8; ++t) {
        float v = aggp[t];
        v += __shfl_xor(v, 16);
        v += __shfl_xor(v, 32);
        if (lane < 16) redw[16 * t + lane] = v;
    }
    __syncthreads();
    if (tid < 128) {
        const float* r0 = reinterpret_cast<const float*>(&e_lds[0][0]);
        const float* r1 = reinterpret_cast<const float*>(&e_lds[1][0]);
        const float* r2 = reinterpret_cast<const float*>(&e_lds[2][0]);
        const float* r3 = reinterpret_cast<const float*>(&e_lds[3][0]);
        agg[(size_t)j * 128 + tid] = (r0[tid] + r1[tid] + r2[tid] + r3[tid]) * s_invdeg;
    }
}

// ---------------------------------------------------------------- update (+ next-round sp, or final out)
template <int LAST>
__global__ __launch_bounds__(256) void k_upd(
                      const float* __restrict__ h_in, const float* __restrict__ agg,
                      const float* __restrict__ Wu, const float* __restrict__ bu,
                      const float* __restrict__ Wa, const float* __restrict__ ba,
                      float* __restrict__ h_out, float* __restrict__ sp,
                      float* __restrict__ out) {
    __shared__ float buf[2][256];
    __shared__ float hn[2][128];
    const int tid = threadIdx.x;
    const int row = tid >> 7, t = tid & 127;
    const int i = blockIdx.x * 2 + row;
    buf[row][t] = h_in[i * 128 + t];
    buf[row][128 + t] = agg[i * 128 + t];
    __syncthreads();
    float acc = bu[t];
#pragma unroll 8
    for (int f = 0; f < 256; ++f) acc += buf[row][f] * Wu[f * 128 + t];
    acc = fmaxf(acc, 0.f);
    if (LAST) {
        out[i * 128 + t] = acc;
    } else {
        h_out[i * 128 + t] = acc;
        hn[row][t] = acc;
        __syncthreads();
        float spv = ba[t];
#pragma unroll 8
        for (int f = 0; f < 128; ++f) spv += hn[row][f] * Wa[f * 128 + t];
        sp[i * 128 + t] = spv;
    }
}

// ---------------------------------------------------------------- graph embedding
__global__ __launch_bounds__(64) void k_gemb(const float* __restrict__ out_h, float* __restrict__ out) {
    int c = blockIdx.x, l = threadIdx.x;
    float acc = 0.f;
    for (int i = l; i < NN; i += 64) acc += out_h[(size_t)i * 128 + c];
#pragma unroll
    for (int off = 32; off; off >>= 1) acc += __shfl_down(acc, off);
    if (l == 0) out[NN * 128 + c] = acc * (1.0f / 768.0f);
}

extern "C" void kernel_launch(void* const* d_in, const int* in_sizes, int n_in,
                              void* d_out, int out_size, void* d_ws, size_t ws_size,
                              hipStream_t stream) {
    const float* nf  = (const float*)d_in[0];
    const float* ef  = (const float*)d_in[1];
    const float* adj = (const float*)d_in[2];
    const float* Wn  = (const float*)d_in[3];
    const float* bn  = (const float*)d_in[4];
    const float* We  = (const float*)d_in[5];
    const float* be  = (const float*)d_in[6];
    const float* Wa  = (const float*)d_in[7];
    const float* ba  = (const float*)d_in[8];
    const float* Wu  = (const float*)d_in[9];
    const float* bu  = (const float*)d_in[10];
    float* out = (float*)d_out;

    // workspace: h | agg | sp | adjT | WeT | Wa2T | efT(bf16)  (~41.3 MB; ws ~302MB)
    float* h_buf = (float*)d_ws;
    float* agg   = h_buf + NN * 128;
    float* sp    = agg + NN * 128;
    float* adjT  = sp + NN * 128;
    unsigned short* WeT  = (unsigned short*)(adjT + NN * NN);
    unsigned short* Wa2T = WeT + 128 * 32;
    unsigned short* efT  = Wa2T + 128 * 128;

    k_prep<<<3344, 256, 0, stream>>>(ef, efT, adj, adjT, We, Wa, WeT, Wa2T,
                                     nf, Wn, bn, ba, h_buf, sp);

    k_big_s<<<NN, 256, 0, stream>>>(efT, adjT, sp, WeT, Wa2T, be, agg);
    k_upd<0><<<NN / 2, 256, 0, stream>>>(h_buf, agg, Wu, bu, Wa, ba, h_buf, sp, out);
    k_big_s<<<NN, 256, 0, stream>>>(efT, adjT, sp, WeT, Wa2T, be, agg);
    k_upd<1><<<NN / 2, 256, 0, stream>>>(h_buf, agg, Wu, bu, Wa, ba, h_buf, sp, out);

    k_gemb<<<128, 64, 0, stream>>>(out, out);
}

// Round 15
// 161.317 us; speedup vs baseline: 1.3593x; 1.3593x over previous
//
#include <hip/hip_runtime.h>
#include <hip/hip_bf16.h>

// GraphSAGE fused kernels for MI355X (gfx950).
// N=768, NODE_IN=64, EDGE_IN=32, H=128, ROUNDS=2.
//
// Round 15: R12 (best: 47us k_big, 139.8 total) with barrier count halved.
// Evidence: R14 (4 fat waves, barrier-free) = 86us >> R12 (8 thin waves,
// 24 barriers) = 47us -> thin waves + occupancy win; remaining cost is the
// per-chunk lockstep. Now 64-row chunk-pairs per phase: gemm1 = 4 MFMA +
// 16 E-writes, gemm2 = 8 ds_read + 16 MFMA between barriers -> 12 barriers
// (was 24), 2x independent work per phase. LDS ~36KB, regs +16 vs R12.

typedef __bf16 bf16x8 __attribute__((ext_vector_type(8)));
typedef float f32x4 __attribute__((ext_vector_type(4)));

#define NN 768

static __device__ __forceinline__ unsigned short to_bf16u(float x) {
    return __builtin_bit_cast(unsigned short, (__bf16)x);
}

// ---------------------------------------------------------------- fused prep
// blocks 0..2303   : ef[i][j][f] fp32 -> efT[j][i][f] bf16 (LDS-tiled)
// blocks 2304..2879: adj transpose (32x32 tiles)
// blocks 2880..2959: weight transposes We->WeT, Wa[H:]->Wa2T (bf16 k-minor)
// blocks 2960..3343: h0 = relu(nf@Wn+bn) and sp = h0@Wa[:H]+ba
__global__ __launch_bounds__(256) void k_prep(
                       const float* __restrict__ ef, unsigned short* __restrict__ efT,
                       const float* __restrict__ adj, float* __restrict__ adjT,
                       const float* __restrict__ We, const float* __restrict__ Wa,
                       unsigned short* __restrict__ WeT, unsigned short* __restrict__ Wa2T,
                       const float* __restrict__ nf, const float* __restrict__ Wn,
                       const float* __restrict__ bn, const float* __restrict__ ba,
                       float* __restrict__ h, float* __restrict__ sp) {
    const int b = blockIdx.x, tid = threadIdx.x;
    if (b < 2304) {
        __shared__ unsigned short tile[8 * 1288 + 8];  // plane 1288, row 40
        const int i0 = (b % 24) * 32, j0 = (b / 24) * 8;
        {
            const int jj = tid >> 5, ff = tid & 31;
#pragma unroll 4
            for (int i = 0; i < 32; ++i) {
                float v = ef[((size_t)(i0 + i) * NN + j0 + jj) * 32 + ff];
                tile[jj * 1288 + i * 40 + ff] = to_bf16u(v);
            }
        }
        __syncthreads();
        const int tp = tid & 31, j = tid >> 5;
        unsigned short* dst = efT + ((size_t)(j0 + j) * NN + i0) * 32;
#pragma unroll
        for (int v = 0; v < 4; ++v) {
            int flat = v * 256 + tp * 8;
            int i = flat >> 5, f = flat & 31;
            bf16x8 val = *reinterpret_cast<const bf16x8*>(&tile[j * 1288 + i * 40 + f]);
            *reinterpret_cast<bf16x8*>(dst + flat) = val;
        }
    } else if (b < 2880) {
        __shared__ float tile[32][33];
        int bb = b - 2304;
        int bx = bb % 24, by = bb / 24;
        int tx = tid & 31, ty = tid >> 5;  // 32 x 8
#pragma unroll
        for (int yy = 0; yy < 32; yy += 8)
            tile[ty + yy][tx] = adj[(size_t)(by * 32 + ty + yy) * NN + bx * 32 + tx];
        __syncthreads();
#pragma unroll
        for (int yy = 0; yy < 32; yy += 8)
            adjT[(size_t)(bx * 32 + ty + yy) * NN + by * 32 + tx] = tile[tx][ty + yy];
    } else if (b < 2960) {
        int g = (b - 2880) * 256 + tid;
        if (g < 128 * 32) {
            int c = g >> 5, f = g & 31;
            WeT[g] = to_bf16u(We[f * 128 + c]);
        } else {
            int g2 = g - 128 * 32;
            int c = g2 >> 7, k = g2 & 127;
            Wa2T[g2] = to_bf16u(Wa[(128 + k) * 128 + c]);
        }
    } else {
        __shared__ float nf_l[2][64];
        __shared__ float h_l[2][128];
        int row = tid >> 7, t = tid & 127;
        int i = (b - 2960) * 2 + row;
        if (t < 64) nf_l[row][t] = nf[i * 64 + t];
        __syncthreads();
        float acc = bn[t];
#pragma unroll 8
        for (int f = 0; f < 64; ++f) acc += nf_l[row][f] * Wn[f * 128 + t];
        acc = fmaxf(acc, 0.f);
        h[i * 128 + t] = acc;
        h_l[row][t] = acc;
        __syncthreads();
        float spv = ba[t];
#pragma unroll 8
        for (int f = 0; f < 128; ++f) spv += h_l[row][f] * Wa[f * 128 + t];
        sp[i * 128 + t] = spv;
    }
}

// ---------------------------------------------------------------- streaming k_big
// Block = receiver j. 8 waves in 2x4 (wr x wc). Phase = 64 sequential
// senders (2 sub-tiles of 16 rows per wave), 12 phases. adj as av multiply.
__global__ __launch_bounds__(512) void k_big_s(
    const unsigned short* __restrict__ efT, const float* __restrict__ adjT,
    const float* __restrict__ sp, const unsigned short* __restrict__ WeT,
    const unsigned short* __restrict__ Wa2T, const float* __restrict__ be,
    float* __restrict__ agg) {
    __shared__ __align__(16) unsigned short e_lds[2][2][32 * 128]; // dbuf x wr, 32KB
    __shared__ float adj_lds[NN];
    __shared__ float be_lds[128];
    __shared__ float wred[8];
    __shared__ float s_invdeg;

    const int tid  = threadIdx.x;
    const int j    = blockIdx.x;
    const int lane = tid & 63;
    const int wv   = tid >> 6;
    const int wr   = wv >> 2;
    const int wc   = wv & 3;
    const int lg   = lane >> 4;
    const int lr   = lane & 15;

    // stage adj column j (coalesced) + degree
    float asum = 0.f;
    for (int k = tid; k < NN; k += 512) {
        float a = adjT[(size_t)j * NN + k];
        adj_lds[k] = a;
        asum += a;
    }
#pragma unroll
    for (int off = 32; off; off >>= 1) asum += __shfl_down(asum, off);
    if (lane == 0) wred[wv] = asum;
    if (tid < 128) be_lds[tid] = be[tid];

    bf16x8 bwe[2];
    bf16x8 bwa[2][4];
#pragma unroll
    for (int t = 0; t < 2; ++t) {
        const int col = 32 * wc + 16 * t + lr;
        bwe[t] = *reinterpret_cast<const bf16x8*>(WeT + col * 32 + 8 * lg);
#pragma unroll
        for (int s = 0; s < 4; ++s)
            bwa[t][s] = *reinterpret_cast<const bf16x8*>(Wa2T + col * 128 + 32 * s + 8 * lg);
    }
    __syncthreads();
    if (tid == 0) {
        float d = 0.f;
#pragma unroll
        for (int w = 0; w < 8; ++w) d += wred[w];
        s_invdeg = 1.0f / fmaxf(d, 1.0f);
    }

    float aggp[2] = {0.f, 0.f};

    // streaming load for phase n, sub-tile s: 16 consecutive rows = 1KB run
    auto load_ef = [&](int n, int sub, bf16x8& x) {
        int row = 64 * n + 32 * wr + 16 * sub + lr;
        x = *reinterpret_cast<const bf16x8*>(efT + ((size_t)j * NN + row) * 32 + 8 * lg);
    };
    // gemm1 for a pair: E(32 rows x 32 cols this wave) -> swizzled e_lds[buf][wr]
    auto gemm1 = [&](bf16x8* a, int buf) {
#pragma unroll
        for (int sub = 0; sub < 2; ++sub) {
#pragma unroll
            for (int t = 0; t < 2; ++t) {
                const int col = 32 * wc + 16 * t + lr;
                float bb = be_lds[col];
                f32x4 c;
                c[0] = bb; c[1] = bb; c[2] = bb; c[3] = bb;
                f32x4 C1 = __builtin_amdgcn_mfma_f32_16x16x32_bf16(a[sub], bwe[t], c, 0, 0, 0);
#pragma unroll
                for (int r = 0; r < 4; ++r) {
                    int row = 16 * sub + 4 * lg + r;
                    int idx = (row * 128 + col) ^ ((row & 7) << 3);
                    e_lds[buf][wr][idx] = to_bf16u(fmaxf(C1[r], 0.f));
                }
            }
        }
    };

    bf16x8 cA[2];
    load_ef(0, 0, cA[0]);
    load_ef(0, 1, cA[1]);
    gemm1(cA, 0);
    load_ef(1, 0, cA[0]);
    load_ef(1, 1, cA[1]);
    __syncthreads();   // E[0] ready

    for (int n = 0; n < 12; ++n) {
        const int b = n & 1;
        bf16x8 pA[2];
        if (n + 2 < 12) {
            load_ef(n + 2, 0, pA[0]);
            load_ef(n + 2, 1, pA[1]);
        }
        if (n + 1 < 12) gemm1(cA, b ^ 1);

        // ---- gemm2 on phase n: 2 sub-tiles from e_lds[b][wr]
#pragma unroll
        for (int sub = 0; sub < 2; ++sub) {
            bf16x8 ae[4];
            const int erow = 16 * sub + lr;
#pragma unroll
            for (int s = 0; s < 4; ++s) {
                int idx = (erow * 128 + 32 * s + 8 * lg) ^ ((erow & 7) << 3);
                ae[s] = *reinterpret_cast<const bf16x8*>(&e_lds[b][wr][idx]);
            }
            const int i0 = 64 * n + 32 * wr + 16 * sub + 4 * lg;
            f32x4 av = *reinterpret_cast<const f32x4*>(&adj_lds[i0]);
#pragma unroll
            for (int t = 0; t < 2; ++t) {
                const int col = 32 * wc + 16 * t + lr;
                f32x4 acc;
#pragma unroll
                for (int r = 0; r < 4; ++r)
                    acc[r] = sp[(size_t)(i0 + r) * 128 + col];
#pragma unroll
                for (int s = 0; s < 4; ++s)
                    acc = __builtin_amdgcn_mfma_f32_16x16x32_bf16(ae[s], bwa[t][s], acc, 0, 0, 0);
#pragma unroll
                for (int r = 0; r < 4; ++r)
                    aggp[t] += fmaxf(acc[r], 0.f) * av[r];
            }
        }

        if (n + 2 < 12) { cA[0] = pA[0]; cA[1] = pA[1]; }
        __syncthreads();
    }

    float* red = reinterpret_cast<float*>(&e_lds[0][0][0]);  // [8][32]
#pragma unroll
    for (int t = 0; t < 2; ++t) {
        float v = aggp[t];
        v += __shfl_xor(v, 16);
        v += __shfl_xor(v, 32);
        if (lane < 16) red[wv * 32 + 16 * t + lane] = v;
    }
    __syncthreads();
    if (tid < 128) {
        int wcol = tid >> 5, c32 = tid & 31;
        agg[(size_t)j * 128 + tid] =
            (red[wcol * 32 + c32] + red[(4 + wcol) * 32 + c32]) * s_invdeg;
    }
}

// ---------------------------------------------------------------- update (+ next-round sp, or final out)
template <int LAST>
__global__ __launch_bounds__(256) void k_upd(
                      const float* __restrict__ h_in, const float* __restrict__ agg,
                      const float* __restrict__ Wu, const float* __restrict__ bu,
                      const float* __restrict__ Wa, const float* __restrict__ ba,
                      float* __restrict__ h_out, float* __restrict__ sp,
                      float* __restrict__ out) {
    __shared__ float buf[2][256];
    __shared__ float hn[2][128];
    const int tid = threadIdx.x;
    const int row = tid >> 7, t = tid & 127;
    const int i = blockIdx.x * 2 + row;
    buf[row][t] = h_in[i * 128 + t];
    buf[row][128 + t] = agg[i * 128 + t];
    __syncthreads();
    float acc = bu[t];
#pragma unroll 8
    for (int f = 0; f < 256; ++f) acc += buf[row][f] * Wu[f * 128 + t];
    acc = fmaxf(acc, 0.f);
    if (LAST) {
        out[i * 128 + t] = acc;
    } else {
        h_out[i * 128 + t] = acc;
        hn[row][t] = acc;
        __syncthreads();
        float spv = ba[t];
#pragma unroll 8
        for (int f = 0; f < 128; ++f) spv += hn[row][f] * Wa[f * 128 + t];
        sp[i * 128 + t] = spv;
    }
}

// ---------------------------------------------------------------- graph embedding
__global__ __launch_bounds__(64) void k_gemb(const float* __restrict__ out_h, float* __restrict__ out) {
    int c = blockIdx.x, l = threadIdx.x;
    float acc = 0.f;
    for (int i = l; i < NN; i += 64) acc += out_h[(size_t)i * 128 + c];
#pragma unroll
    for (int off = 32; off; off >>= 1) acc += __shfl_down(acc, off);
    if (l == 0) out[NN * 128 + c] = acc * (1.0f / 768.0f);
}

extern "C" void kernel_launch(void* const* d_in, const int* in_sizes, int n_in,
                              void* d_out, int out_size, void* d_ws, size_t ws_size,
                              hipStream_t stream) {
    const float* nf  = (const float*)d_in[0];
    const float* ef  = (const float*)d_in[1];
    const float* adj = (const float*)d_in[2];
    const float* Wn  = (const float*)d_in[3];
    const float* bn  = (const float*)d_in[4];
    const float* We  = (const float*)d_in[5];
    const float* be  = (const float*)d_in[6];
    const float* Wa  = (const float*)d_in[7];
    const float* ba  = (const float*)d_in[8];
    const float* Wu  = (const float*)d_in[9];
    const float* bu  = (const float*)d_in[10];
    float* out = (float*)d_out;

    // workspace: h | agg | sp | adjT | WeT | Wa2T | efT(bf16)  (~41.3 MB; ws ~302MB)
    float* h_buf = (float*)d_ws;
    float* agg   = h_buf + NN * 128;
    float* sp    = agg + NN * 128;
    float* adjT  = sp + NN * 128;
    unsigned short* WeT  = (unsigned short*)(adjT + NN * NN);
    unsigned short* Wa2T = WeT + 128 * 32;
    unsigned short* efT  = Wa2T + 128 * 128;

    k_prep<<<3344, 256, 0, stream>>>(ef, efT, adj, adjT, We, Wa, WeT, Wa2T,
                                     nf, Wn, bn, ba, h_buf, sp);

    k_big_s<<<NN, 512, 0, stream>>>(efT, adjT, sp, WeT, Wa2T, be, agg);
    k_upd<0><<<NN / 2, 256, 0, stream>>>(h_buf, agg, Wu, bu, Wa, ba, h_buf, sp, out);
    k_big_s<<<NN, 512, 0, stream>>>(efT, adjT, sp, WeT, Wa2T, be, agg);
    k_upd<1><<<NN / 2, 256, 0, stream>>>(h_buf, agg, Wu, bu, Wa, ba, h_buf, sp, out);

    k_gemb<<<128, 64, 0, stream>>>(out, out);
}

// Round 16
// 152.625 us; speedup vs baseline: 1.4367x; 1.0569x over previous
//
#include <hip/hip_runtime.h>
#include <hip/hip_bf16.h>

// GraphSAGE fused kernels for MI355X (gfx950).
// N=768, NODE_IN=64, EDGE_IN=32, H=128, ROUNDS=2.
//
// Round 16: materialize round-invariant eproj = relu(ef@We+be)@Wa2 in bf16
// (151MB, ws is ~288MiB). R12-R15 showed the fused recompute is stuck at
// MfmaUtil ~20% (47us/round). Now: k_build = dense GEMM over contiguous
// flat (i,j) rows (perfectly coalesced, no gather/mask, 4 barriers/block);
// k_round = pure streaming relu(sp+eproj)*adj reduction (4KB contiguous
// runs, HBM/L3 rate; round 2 L3-resident); k_upd fuses the 16-seg partial
// reduce. efT/adjT deleted.

typedef __bf16 bf16x8 __attribute__((ext_vector_type(8)));
typedef float f32x4 __attribute__((ext_vector_type(4)));

#define NN 768

static __device__ __forceinline__ unsigned short to_bf16u(float x) {
    return __builtin_bit_cast(unsigned short, (__bf16)x);
}

// ---------------------------------------------------------------- fused prep
// blocks 0..79   : weight transposes We->WeT, Wa[H:]->Wa2T (bf16 k-minor)
// blocks 80..463 : h0 = relu(nf@Wn+bn) and sp = h0@Wa[:H]+ba
// blocks 464..475: invdeg[j] = 1/max(sum_i adj[i][j], 1)
__global__ __launch_bounds__(256) void k_prep(
                       const float* __restrict__ adj,
                       const float* __restrict__ We, const float* __restrict__ Wa,
                       unsigned short* __restrict__ WeT, unsigned short* __restrict__ Wa2T,
                       const float* __restrict__ nf, const float* __restrict__ Wn,
                       const float* __restrict__ bn, const float* __restrict__ ba,
                       float* __restrict__ h, float* __restrict__ sp,
                       float* __restrict__ invdeg) {
    const int b = blockIdx.x, tid = threadIdx.x;
    if (b < 80) {
        int g = b * 256 + tid;
        if (g < 128 * 32) {
            int c = g >> 5, f = g & 31;
            WeT[g] = to_bf16u(We[f * 128 + c]);
        } else {
            int g2 = g - 128 * 32;
            int c = g2 >> 7, k = g2 & 127;
            Wa2T[g2] = to_bf16u(Wa[(128 + k) * 128 + c]);
        }
    } else if (b < 464) {
        __shared__ float nf_l[2][64];
        __shared__ float h_l[2][128];
        int row = tid >> 7, t = tid & 127;
        int i = (b - 80) * 2 + row;
        if (t < 64) nf_l[row][t] = nf[i * 64 + t];
        __syncthreads();
        float acc = bn[t];
#pragma unroll 8
        for (int f = 0; f < 64; ++f) acc += nf_l[row][f] * Wn[f * 128 + t];
        acc = fmaxf(acc, 0.f);
        h[i * 128 + t] = acc;
        h_l[row][t] = acc;
        __syncthreads();
        float spv = ba[t];
#pragma unroll 8
        for (int f = 0; f < 128; ++f) spv += h_l[row][f] * Wa[f * 128 + t];
        sp[i * 128 + t] = spv;
    } else {
        __shared__ float dsum[4][64];
        int d = b - 464;
        int q = tid >> 6, jj = tid & 63;
        int j = d * 64 + jj;
        float s = 0.f;
        for (int i = q * 192; i < q * 192 + 192; ++i)
            s += adj[(size_t)i * NN + j];
        dsum[q][jj] = s;
        __syncthreads();
        if (tid < 64) {
            float tot = dsum[0][tid] + dsum[1][tid] + dsum[2][tid] + dsum[3][tid];
            invdeg[d * 64 + tid] = 1.0f / fmaxf(tot, 1.0f);
        }
    }
}

// ---------------------------------------------------------------- eproj build
// Block = 128 consecutive flat rows g = i*768+j. 8 waves in 2x4 (wr = 64-row
// half, wc = 32-col quarter). eproj[g][k] = (relu(ef[g]@We + be)) @ Wa2, bf16.
__global__ __launch_bounds__(512) void k_build(
    const float* __restrict__ ef, const unsigned short* __restrict__ WeT,
    const unsigned short* __restrict__ Wa2T, const float* __restrict__ be,
    unsigned short* __restrict__ eproj) {
    __shared__ unsigned short ef_lds[128 * 40];                 // 10KB, pad 40
    __shared__ __align__(16) unsigned short e_lds[128 * 128];   // 32KB swizzled, reused for out
    const int tid  = threadIdx.x;
    const size_t g0 = (size_t)blockIdx.x * 128;
    const int lane = tid & 63;
    const int wv   = tid >> 6;
    const int wr   = wv >> 2;
    const int wc   = wv & 3;
    const int lg   = lane >> 4;
    const int lr   = lane & 15;

    // ---- stage ef rows (fp32 -> bf16), fully coalesced 16KB read
    {
        int row = tid >> 2, c0 = (tid & 3) * 8;
        const float* src = ef + (g0 + row) * 32 + c0;
        float4 f0 = *reinterpret_cast<const float4*>(src);
        float4 f1 = *reinterpret_cast<const float4*>(src + 4);
        bf16x8 v;
        v[0] = (__bf16)f0.x; v[1] = (__bf16)f0.y; v[2] = (__bf16)f0.z; v[3] = (__bf16)f0.w;
        v[4] = (__bf16)f1.x; v[5] = (__bf16)f1.y; v[6] = (__bf16)f1.z; v[7] = (__bf16)f1.w;
        *reinterpret_cast<bf16x8*>(&ef_lds[row * 40 + c0]) = v;
    }
    // ---- B-frags in regs
    bf16x8 bwe[2];
    bf16x8 bwa[2][4];
    float bereg[2];
#pragma unroll
    for (int t = 0; t < 2; ++t) {
        const int col = 32 * wc + 16 * t + lr;
        bwe[t] = *reinterpret_cast<const bf16x8*>(WeT + col * 32 + 8 * lg);
        bereg[t] = be[col];
#pragma unroll
        for (int s = 0; s < 4; ++s)
            bwa[t][s] = *reinterpret_cast<const bf16x8*>(Wa2T + col * 128 + 32 * s + 8 * lg);
    }
    __syncthreads();   // A: ef_lds ready

    // ---- GEMM1: E(64 rows x 32 cols per wave) = relu(EF @ We + be)
#pragma unroll
    for (int s = 0; s < 4; ++s) {
        const int arow = 64 * wr + 16 * s + lr;
        bf16x8 a = *reinterpret_cast<const bf16x8*>(&ef_lds[arow * 40 + 8 * lg]);
#pragma unroll
        for (int t = 0; t < 2; ++t) {
            const int col = 32 * wc + 16 * t + lr;
            f32x4 c;
            c[0] = bereg[t]; c[1] = bereg[t]; c[2] = bereg[t]; c[3] = bereg[t];
            f32x4 C1 = __builtin_amdgcn_mfma_f32_16x16x32_bf16(a, bwe[t], c, 0, 0, 0);
#pragma unroll
            for (int r = 0; r < 4; ++r) {
                int row = 64 * wr + 16 * s + 4 * lg + r;
                int idx = (row * 128 + col) ^ ((row & 7) << 3);
                e_lds[idx] = to_bf16u(fmaxf(C1[r], 0.f));
            }
        }
    }
    __syncthreads();   // B: E ready

    // ---- GEMM2: out(64 x 32 per wave) = E @ Wa2, hold packed bf16 in regs
    ushort4 outv[4][2];
#pragma unroll
    for (int s = 0; s < 4; ++s) {
        const int arow = 64 * wr + 16 * s + lr;
        bf16x8 ae[4];
#pragma unroll
        for (int ss = 0; ss < 4; ++ss) {
            int idx = (arow * 128 + 32 * ss + 8 * lg) ^ ((arow & 7) << 3);
            ae[ss] = *reinterpret_cast<const bf16x8*>(&e_lds[idx]);
        }
#pragma unroll
        for (int t = 0; t < 2; ++t) {
            f32x4 acc;
            acc[0] = 0.f; acc[1] = 0.f; acc[2] = 0.f; acc[3] = 0.f;
#pragma unroll
            for (int ss = 0; ss < 4; ++ss)
                acc = __builtin_amdgcn_mfma_f32_16x16x32_bf16(ae[ss], bwa[t][ss], acc, 0, 0, 0);
            outv[s][t].x = to_bf16u(acc[0]);
            outv[s][t].y = to_bf16u(acc[1]);
            outv[s][t].z = to_bf16u(acc[2]);
            outv[s][t].w = to_bf16u(acc[3]);
        }
    }
    __syncthreads();   // C: all E reads done, reuse e_lds for output staging

#pragma unroll
    for (int s = 0; s < 4; ++s)
#pragma unroll
        for (int t = 0; t < 2; ++t) {
            const int col = 32 * wc + 16 * t + lr;
#pragma unroll
            for (int r = 0; r < 4; ++r) {
                int row = 64 * wr + 16 * s + 4 * lg + r;
                int idx = (row * 128 + col) ^ ((row & 7) << 3);
                unsigned short val = (r == 0) ? outv[s][t].x : (r == 1) ? outv[s][t].y
                                   : (r == 2) ? outv[s][t].z : outv[s][t].w;
                e_lds[idx] = val;
            }
        }
    __syncthreads();   // D: out staged

    // ---- coalesced global write: 128 rows x 256B
    {
        int row = tid >> 2;
#pragma unroll
        for (int m = 0; m < 4; ++m) {
            int a = (tid & 3) + 4 * m;
            int idx = row * 128 + 8 * (a ^ (row & 7));
            f32x4 v = *reinterpret_cast<const f32x4*>(&e_lds[idx]);
            *reinterpret_cast<f32x4*>(eproj + (g0 + row) * 128 + 8 * a) = v;
        }
    }
}

// ---------------------------------------------------------------- streaming round
// Block b: jt = b>>4 (16 receivers j0=jt*16), seg = b&15 (48 senders).
// acc[j][k] += relu(sp[i][k] + eproj[i*768+j][k]) * adj[i][j].
__global__ __launch_bounds__(256) void k_round(
    const unsigned short* __restrict__ eproj, const float* __restrict__ adj,
    const float* __restrict__ sp, float* __restrict__ aggp) {
    const int tid = threadIdx.x;
    const int jt  = blockIdx.x >> 4;
    const int seg = blockIdx.x & 15;
    const int j0  = jt * 16;
    const int i0  = seg * 48;
    const int jj  = tid >> 4;
    const int kb  = (tid & 15) * 8;

    const size_t estep = (size_t)NN * 128;
    const unsigned short* ep = eproj + ((size_t)i0 * NN + j0 + jj) * 128 + kb;
    const float* ap = adj + (size_t)i0 * NN + j0 + jj;
    const float* spp = sp + (size_t)i0 * 128 + kb;

    float acc[8] = {0.f, 0.f, 0.f, 0.f, 0.f, 0.f, 0.f, 0.f};

    bf16x8 v = *reinterpret_cast<const bf16x8*>(ep);
    float av = *ap;
    float4 s0 = *reinterpret_cast<const float4*>(spp);
    float4 s1 = *reinterpret_cast<const float4*>(spp + 4);

    for (int m = 0; m < 48; ++m) {
        bf16x8 vn = v; float avn = av; float4 s0n = s0, s1n = s1;
        if (m < 47) {
            vn = *reinterpret_cast<const bf16x8*>(ep + estep);
            avn = ap[NN];
            s0n = *reinterpret_cast<const float4*>(spp + 128);
            s1n = *reinterpret_cast<const float4*>(spp + 132);
        }
        acc[0] += fmaxf(s0.x + (float)v[0], 0.f) * av;
        acc[1] += fmaxf(s0.y + (float)v[1], 0.f) * av;
        acc[2] += fmaxf(s0.z + (float)v[2], 0.f) * av;
        acc[3] += fmaxf(s0.w + (float)v[3], 0.f) * av;
        acc[4] += fmaxf(s1.x + (float)v[4], 0.f) * av;
        acc[5] += fmaxf(s1.y + (float)v[5], 0.f) * av;
        acc[6] += fmaxf(s1.z + (float)v[6], 0.f) * av;
        acc[7] += fmaxf(s1.w + (float)v[7], 0.f) * av;
        ep += estep; ap += NN; spp += 128;
        v = vn; av = avn; s0 = s0n; s1 = s1n;
    }

    float* dst = aggp + ((size_t)(j0 + jj) * 16 + seg) * 128 + kb;
    float4 o0, o1;
    o0.x = acc[0]; o0.y = acc[1]; o0.z = acc[2]; o0.w = acc[3];
    o1.x = acc[4]; o1.y = acc[5]; o1.z = acc[6]; o1.w = acc[7];
    *reinterpret_cast<float4*>(dst) = o0;
    *reinterpret_cast<float4*>(dst + 4) = o1;
}

// ---------------------------------------------------------------- update (reduce partials + GEMM)
template <int LAST>
__global__ __launch_bounds__(256) void k_upd(
                      const float* __restrict__ h_in, const float* __restrict__ aggp,
                      const float* __restrict__ invdeg,
                      const float* __restrict__ Wu, const float* __restrict__ bu,
                      const float* __restrict__ Wa, const float* __restrict__ ba,
                      float* __restrict__ h_out, float* __restrict__ sp,
                      float* __restrict__ out) {
    __shared__ float buf[2][256];
    __shared__ float hn[2][128];
    const int tid = threadIdx.x;
    const int row = tid >> 7, t = tid & 127;
    const int j = blockIdx.x * 2 + row;
    float s = 0.f;
#pragma unroll
    for (int seg = 0; seg < 16; ++seg)
        s += aggp[((size_t)j * 16 + seg) * 128 + t];
    buf[row][t] = h_in[j * 128 + t];
    buf[row][128 + t] = s * invdeg[j];
    __syncthreads();
    float acc = bu[t];
#pragma unroll 8
    for (int f = 0; f < 256; ++f) acc += buf[row][f] * Wu[f * 128 + t];
    acc = fmaxf(acc, 0.f);
    if (LAST) {
        out[j * 128 + t] = acc;
    } else {
        h_out[j * 128 + t] = acc;
        hn[row][t] = acc;
        __syncthreads();
        float spv = ba[t];
#pragma unroll 8
        for (int f = 0; f < 128; ++f) spv += hn[row][f] * Wa[f * 128 + t];
        sp[j * 128 + t] = spv;
    }
}

// ---------------------------------------------------------------- graph embedding
__global__ __launch_bounds__(64) void k_gemb(const float* __restrict__ out_h, float* __restrict__ out) {
    int c = blockIdx.x, l = threadIdx.x;
    float acc = 0.f;
    for (int i = l; i < NN; i += 64) acc += out_h[(size_t)i * 128 + c];
#pragma unroll
    for (int off = 32; off; off >>= 1) acc += __shfl_down(acc, off);
    if (l == 0) out[NN * 128 + c] = acc * (1.0f / 768.0f);
}

extern "C" void kernel_launch(void* const* d_in, const int* in_sizes, int n_in,
                              void* d_out, int out_size, void* d_ws, size_t ws_size,
                              hipStream_t stream) {
    const float* nf  = (const float*)d_in[0];
    const float* ef  = (const float*)d_in[1];
    const float* adj = (const float*)d_in[2];
    const float* Wn  = (const float*)d_in[3];
    const float* bn  = (const float*)d_in[4];
    const float* We  = (const float*)d_in[5];
    const float* be  = (const float*)d_in[6];
    const float* Wa  = (const float*)d_in[7];
    const float* ba  = (const float*)d_in[8];
    const float* Wu  = (const float*)d_in[9];
    const float* bu  = (const float*)d_in[10];
    float* out = (float*)d_out;

    // ws layout (floats): h | sp | invdeg | aggp | WeT(us) | Wa2T(us) | eproj(us)
    float* h_buf  = (float*)d_ws;
    float* sp     = h_buf + NN * 128;
    float* invdeg = sp + NN * 128;
    float* aggp   = invdeg + NN;
    unsigned short* WeT   = (unsigned short*)(aggp + (size_t)NN * 16 * 128);
    unsigned short* Wa2T  = WeT + 128 * 32;
    unsigned short* eproj = Wa2T + 128 * 128;

    k_prep<<<476, 256, 0, stream>>>(adj, We, Wa, WeT, Wa2T, nf, Wn, bn, ba,
                                    h_buf, sp, invdeg);
    k_build<<<NN * NN / 128, 512, 0, stream>>>(ef, WeT, Wa2T, be, eproj);

    k_round<<<48 * 16, 256, 0, stream>>>(eproj, adj, sp, aggp);
    k_upd<0><<<NN / 2, 256, 0, stream>>>(h_buf, aggp, invdeg, Wu, bu, Wa, ba, h_buf, sp, out);
    k_round<<<48 * 16, 256, 0, stream>>>(eproj, adj, sp, aggp);
    k_upd<1><<<NN / 2, 256, 0, stream>>>(h_buf, aggp, invdeg, Wu, bu, Wa, ba, h_buf, sp, out);

    k_gemb<<<128, 64, 0, stream>>>(out, out);
}

// Round 17
// 151.216 us; speedup vs baseline: 1.4501x; 1.0093x over previous
//
#include <hip/hip_runtime.h>
#include <hip/hip_bf16.h>

// GraphSAGE fused kernels for MI355X (gfx950).
// N=768, NODE_IN=64, EDGE_IN=32, H=128, ROUNDS=2.
//
// Round 17: eproj-materialization strategy (R16) with k_build rebuilt on
// R12's looped schedule: block = sender i, 24 chunks of 32 j-rows, double-
// buffered E, 1 barrier/chunk. A-frags direct from ef (contiguous 128B
// rows, no input staging); GEMM2 with SWAPPED operands (mfma(bwa, ae) =
// out^T) so each lane holds 4 contiguous k -> direct ushort4 stores, no
// output restage (R16's 4-barrier one-shot block was chain-bound: 76.8us,
// MfmaUtil 12%). k_round/k_upd/k_prep unchanged (verified).

typedef __bf16 bf16x8 __attribute__((ext_vector_type(8)));
typedef float f32x4 __attribute__((ext_vector_type(4)));

#define NN 768

static __device__ __forceinline__ unsigned short to_bf16u(float x) {
    return __builtin_bit_cast(unsigned short, (__bf16)x);
}

// ---------------------------------------------------------------- fused prep
// blocks 0..79   : weight transposes We->WeT, Wa[H:]->Wa2T (bf16 k-minor)
// blocks 80..463 : h0 = relu(nf@Wn+bn) and sp = h0@Wa[:H]+ba
// blocks 464..475: invdeg[j] = 1/max(sum_i adj[i][j], 1)
__global__ __launch_bounds__(256) void k_prep(
                       const float* __restrict__ adj,
                       const float* __restrict__ We, const float* __restrict__ Wa,
                       unsigned short* __restrict__ WeT, unsigned short* __restrict__ Wa2T,
                       const float* __restrict__ nf, const float* __restrict__ Wn,
                       const float* __restrict__ bn, const float* __restrict__ ba,
                       float* __restrict__ h, float* __restrict__ sp,
                       float* __restrict__ invdeg) {
    const int b = blockIdx.x, tid = threadIdx.x;
    if (b < 80) {
        int g = b * 256 + tid;
        if (g < 128 * 32) {
            int c = g >> 5, f = g & 31;
            WeT[g] = to_bf16u(We[f * 128 + c]);
        } else {
            int g2 = g - 128 * 32;
            int c = g2 >> 7, k = g2 & 127;
            Wa2T[g2] = to_bf16u(Wa[(128 + k) * 128 + c]);
        }
    } else if (b < 464) {
        __shared__ float nf_l[2][64];
        __shared__ float h_l[2][128];
        int row = tid >> 7, t = tid & 127;
        int i = (b - 80) * 2 + row;
        if (t < 64) nf_l[row][t] = nf[i * 64 + t];
        __syncthreads();
        float acc = bn[t];
#pragma unroll 8
        for (int f = 0; f < 64; ++f) acc += nf_l[row][f] * Wn[f * 128 + t];
        acc = fmaxf(acc, 0.f);
        h[i * 128 + t] = acc;
        h_l[row][t] = acc;
        __syncthreads();
        float spv = ba[t];
#pragma unroll 8
        for (int f = 0; f < 128; ++f) spv += h_l[row][f] * Wa[f * 128 + t];
        sp[i * 128 + t] = spv;
    } else {
        __shared__ float dsum[4][64];
        int d = b - 464;
        int q = tid >> 6, jj = tid & 63;
        int j = d * 64 + jj;
        float s = 0.f;
        for (int i = q * 192; i < q * 192 + 192; ++i)
            s += adj[(size_t)i * NN + j];
        dsum[q][jj] = s;
        __syncthreads();
        if (tid < 64) {
            float tot = dsum[0][tid] + dsum[1][tid] + dsum[2][tid] + dsum[3][tid];
            invdeg[d * 64 + tid] = 1.0f / fmaxf(tot, 1.0f);
        }
    }
}

// ---------------------------------------------------------------- eproj build (looped)
// Block = sender i. 8 waves in 2x4 (wr = 16-row half of the 32-j chunk,
// wc = 32-col quarter). 24 chunks, double-buffered E, 1 barrier/chunk.
// eproj[i*768+j][k] = (relu(ef[i][j]@We + be)) @ Wa2, bf16.
__global__ __launch_bounds__(512) void k_build(
    const float* __restrict__ ef, const unsigned short* __restrict__ WeT,
    const unsigned short* __restrict__ Wa2T, const float* __restrict__ be,
    unsigned short* __restrict__ eproj) {
    __shared__ __align__(16) unsigned short e_lds[2][32 * 128];  // 16KB dbuf
    const int tid  = threadIdx.x;
    const int lane = tid & 63;
    const int wv   = tid >> 6;
    const int wr   = wv >> 2;
    const int wc   = wv & 3;
    const int lg   = lane >> 4;
    const int lr   = lane & 15;
    const size_t gbase = (size_t)blockIdx.x * NN;

    // B-frags in regs
    bf16x8 bwe[2];
    bf16x8 bwa[2][4];
    float bereg[2];
#pragma unroll
    for (int t = 0; t < 2; ++t) {
        const int col = 32 * wc + 16 * t + lr;
        bwe[t] = *reinterpret_cast<const bf16x8*>(WeT + col * 32 + 8 * lg);
        bereg[t] = be[col];
#pragma unroll
        for (int s = 0; s < 4; ++s)
            bwa[t][s] = *reinterpret_cast<const bf16x8*>(Wa2T + col * 128 + 32 * s + 8 * lg);
    }

    // A-frag direct from ef: rows are contiguous 128B, wave = 2KB coalesced
    auto load_a = [&](int n, bf16x8& x) {
        const float* p = ef + (gbase + 32 * n + 16 * wr + lr) * 32 + 8 * lg;
        float4 f0 = *reinterpret_cast<const float4*>(p);
        float4 f1 = *reinterpret_cast<const float4*>(p + 4);
        x[0] = (__bf16)f0.x; x[1] = (__bf16)f0.y; x[2] = (__bf16)f0.z; x[3] = (__bf16)f0.w;
        x[4] = (__bf16)f1.x; x[5] = (__bf16)f1.y; x[6] = (__bf16)f1.z; x[7] = (__bf16)f1.w;
    };
    // GEMM1: E(16 rows x 32 cols per wave) = relu(EF @ We + be) -> swizzled
    auto gemm1 = [&](bf16x8 a, int buf) {
#pragma unroll
        for (int t = 0; t < 2; ++t) {
            const int col = 32 * wc + 16 * t + lr;
            f32x4 c;
            c[0] = bereg[t]; c[1] = bereg[t]; c[2] = bereg[t]; c[3] = bereg[t];
            f32x4 C1 = __builtin_amdgcn_mfma_f32_16x16x32_bf16(a, bwe[t], c, 0, 0, 0);
#pragma unroll
            for (int r = 0; r < 4; ++r) {
                int row = 16 * wr + 4 * lg + r;
                int idx = (row * 128 + col) ^ ((row & 7) << 3);
                e_lds[buf][idx] = to_bf16u(fmaxf(C1[r], 0.f));
            }
        }
    };

    bf16x8 cA, pA;
    load_a(0, cA);
    gemm1(cA, 0);
    load_a(1, cA);
    __syncthreads();   // E[0] ready

    for (int n = 0; n < 24; ++n) {
        const int b = n & 1;
        if (n + 2 < 24) load_a(n + 2, pA);
        if (n + 1 < 24) gemm1(cA, b ^ 1);

        // GEMM2 (swapped operands -> out^T, k-contiguous per lane)
        bf16x8 ae[4];
        const int erow = 16 * wr + lr;
#pragma unroll
        for (int s = 0; s < 4; ++s) {
            int idx = (erow * 128 + 32 * s + 8 * lg) ^ ((erow & 7) << 3);
            ae[s] = *reinterpret_cast<const bf16x8*>(&e_lds[b][idx]);
        }
        unsigned short* orow = eproj + (gbase + 32 * n + 16 * wr + lr) * 128;
#pragma unroll
        for (int t = 0; t < 2; ++t) {
            f32x4 acc;
            acc[0] = 0.f; acc[1] = 0.f; acc[2] = 0.f; acc[3] = 0.f;
#pragma unroll
            for (int s = 0; s < 4; ++s)
                acc = __builtin_amdgcn_mfma_f32_16x16x32_bf16(bwa[t][s], ae[s], acc, 0, 0, 0);
            ushort4 o;
            o.x = to_bf16u(acc[0]); o.y = to_bf16u(acc[1]);
            o.z = to_bf16u(acc[2]); o.w = to_bf16u(acc[3]);
            *reinterpret_cast<ushort4*>(orow + 32 * wc + 16 * t + 4 * lg) = o;
        }

        if (n + 2 < 24) cA = pA;
        __syncthreads();
    }
}

// ---------------------------------------------------------------- streaming round
// Block b: jt = b>>4 (16 receivers j0=jt*16), seg = b&15 (48 senders).
// acc[j][k] += relu(sp[i][k] + eproj[i*768+j][k]) * adj[i][j].
__global__ __launch_bounds__(256) void k_round(
    const unsigned short* __restrict__ eproj, const float* __restrict__ adj,
    const float* __restrict__ sp, float* __restrict__ aggp) {
    const int tid = threadIdx.x;
    const int jt  = blockIdx.x >> 4;
    const int seg = blockIdx.x & 15;
    const int j0  = jt * 16;
    const int i0  = seg * 48;
    const int jj  = tid >> 4;
    const int kb  = (tid & 15) * 8;

    const size_t estep = (size_t)NN * 128;
    const unsigned short* ep = eproj + ((size_t)i0 * NN + j0 + jj) * 128 + kb;
    const float* ap = adj + (size_t)i0 * NN + j0 + jj;
    const float* spp = sp + (size_t)i0 * 128 + kb;

    float acc[8] = {0.f, 0.f, 0.f, 0.f, 0.f, 0.f, 0.f, 0.f};

    bf16x8 v = *reinterpret_cast<const bf16x8*>(ep);
    float av = *ap;
    float4 s0 = *reinterpret_cast<const float4*>(spp);
    float4 s1 = *reinterpret_cast<const float4*>(spp + 4);

    for (int m = 0; m < 48; ++m) {
        bf16x8 vn = v; float avn = av; float4 s0n = s0, s1n = s1;
        if (m < 47) {
            vn = *reinterpret_cast<const bf16x8*>(ep + estep);
            avn = ap[NN];
            s0n = *reinterpret_cast<const float4*>(spp + 128);
            s1n = *reinterpret_cast<const float4*>(spp + 132);
        }
        acc[0] += fmaxf(s0.x + (float)v[0], 0.f) * av;
        acc[1] += fmaxf(s0.y + (float)v[1], 0.f) * av;
        acc[2] += fmaxf(s0.z + (float)v[2], 0.f) * av;
        acc[3] += fmaxf(s0.w + (float)v[3], 0.f) * av;
        acc[4] += fmaxf(s1.x + (float)v[4], 0.f) * av;
        acc[5] += fmaxf(s1.y + (float)v[5], 0.f) * av;
        acc[6] += fmaxf(s1.z + (float)v[6], 0.f) * av;
        acc[7] += fmaxf(s1.w + (float)v[7], 0.f) * av;
        ep += estep; ap += NN; spp += 128;
        v = vn; av = avn; s0 = s0n; s1 = s1n;
    }

    float* dst = aggp + ((size_t)(j0 + jj) * 16 + seg) * 128 + kb;
    float4 o0, o1;
    o0.x = acc[0]; o0.y = acc[1]; o0.z = acc[2]; o0.w = acc[3];
    o1.x = acc[4]; o1.y = acc[5]; o1.z = acc[6]; o1.w = acc[7];
    *reinterpret_cast<float4*>(dst) = o0;
    *reinterpret_cast<float4*>(dst + 4) = o1;
}

// ---------------------------------------------------------------- update (reduce partials + GEMM)
template <int LAST>
__global__ __launch_bounds__(256) void k_upd(
                      const float* __restrict__ h_in, const float* __restrict__ aggp,
                      const float* __restrict__ invdeg,
                      const float* __restrict__ Wu, const float* __restrict__ bu,
                      const float* __restrict__ Wa, const float* __restrict__ ba,
                      float* __restrict__ h_out, float* __restrict__ sp,
                      float* __restrict__ out) {
    __shared__ float buf[2][256];
    __shared__ float hn[2][128];
    const int tid = threadIdx.x;
    const int row = tid >> 7, t = tid & 127;
    const int j = blockIdx.x * 2 + row;
    float s = 0.f;
#pragma unroll
    for (int seg = 0; seg < 16; ++seg)
        s += aggp[((size_t)j * 16 + seg) * 128 + t];
    buf[row][t] = h_in[j * 128 + t];
    buf[row][128 + t] = s * invdeg[j];
    __syncthreads();
    float acc = bu[t];
#pragma unroll 8
    for (int f = 0; f < 256; ++f) acc += buf[row][f] * Wu[f * 128 + t];
    acc = fmaxf(acc, 0.f);
    if (LAST) {
        out[j * 128 + t] = acc;
    } else {
        h_out[j * 128 + t] = acc;
        hn[row][t] = acc;
        __syncthreads();
        float spv = ba[t];
#pragma unroll 8
        for (int f = 0; f < 128; ++f) spv += hn[row][f] * Wa[f * 128 + t];
        sp[j * 128 + t] = spv;
    }
}

// ---------------------------------------------------------------- graph embedding
__global__ __launch_bounds__(64) void k_gemb(const float* __restrict__ out_h, float* __restrict__ out) {
    int c = blockIdx.x, l = threadIdx.x;
    float acc = 0.f;
    for (int i = l; i < NN; i += 64) acc += out_h[(size_t)i * 128 + c];
#pragma unroll
    for (int off = 32; off; off >>= 1) acc += __shfl_down(acc, off);
    if (l == 0) out[NN * 128 + c] = acc * (1.0f / 768.0f);
}

extern "C" void kernel_launch(void* const* d_in, const int* in_sizes, int n_in,
                              void* d_out, int out_size, void* d_ws, size_t ws_size,
                              hipStream_t stream) {
    const float* nf  = (const float*)d_in[0];
    const float* ef  = (const float*)d_in[1];
    const float* adj = (const float*)d_in[2];
    const float* Wn  = (const float*)d_in[3];
    const float* bn  = (const float*)d_in[4];
    const float* We  = (const float*)d_in[5];
    const float* be  = (const float*)d_in[6];
    const float* Wa  = (const float*)d_in[7];
    const float* ba  = (const float*)d_in[8];
    const float* Wu  = (const float*)d_in[9];
    const float* bu  = (const float*)d_in[10];
    float* out = (float*)d_out;

    // ws layout (floats): h | sp | invdeg | aggp | WeT(us) | Wa2T(us) | eproj(us)
    float* h_buf  = (float*)d_ws;
    float* sp     = h_buf + NN * 128;
    float* invdeg = sp + NN * 128;
    float* aggp   = invdeg + NN;
    unsigned short* WeT   = (unsigned short*)(aggp + (size_t)NN * 16 * 128);
    unsigned short* Wa2T  = WeT + 128 * 32;
    unsigned short* eproj = Wa2T + 128 * 128;

    k_prep<<<476, 256, 0, stream>>>(adj, We, Wa, WeT, Wa2T, nf, Wn, bn, ba,
                                    h_buf, sp, invdeg);
    k_build<<<NN, 512, 0, stream>>>(ef, WeT, Wa2T, be, eproj);

    k_round<<<48 * 16, 256, 0, stream>>>(eproj, adj, sp, aggp);
    k_upd<0><<<NN / 2, 256, 0, stream>>>(h_buf, aggp, invdeg, Wu, bu, Wa, ba, h_buf, sp, out);
    k_round<<<48 * 16, 256, 0, stream>>>(eproj, adj, sp, aggp);
    k_upd<1><<<NN / 2, 256, 0, stream>>>(h_buf, aggp, invdeg, Wu, bu, Wa, ba, h_buf, sp, out);

    k_gemb<<<128, 64, 0, stream>>>(out, out);
}

// Round 18
// 144.164 us; speedup vs baseline: 1.5210x; 1.0489x over previous
//
#include <hip/hip_runtime.h>
#include <hip/hip_bf16.h>

// GraphSAGE fused kernels for MI355X (gfx950).
// N=768, NODE_IN=64, EDGE_IN=32, H=128, ROUNDS=2.
//
// Round 18: eproj materialization with k_build = R17's looped double-buffer
// pipeline + R16's LDS-staged coalesced stores (R17's direct 8B stores were
// 32B-fragment scatter: 1.95 TB/s, 98us; R16's coalesced one-shot was 2.46
// TB/s but chain-bound: 77us). One barrier per 32-row chunk; e_lds and
// o_lds double-buffered; store = 16B/lane, 4KB contiguous per wave.
// k_prep/k_round/k_upd unchanged (verified).

typedef __bf16 bf16x8 __attribute__((ext_vector_type(8)));
typedef float f32x4 __attribute__((ext_vector_type(4)));

#define NN 768

static __device__ __forceinline__ unsigned short to_bf16u(float x) {
    return __builtin_bit_cast(unsigned short, (__bf16)x);
}

// ---------------------------------------------------------------- fused prep
// blocks 0..79   : weight transposes We->WeT, Wa[H:]->Wa2T (bf16 k-minor)
// blocks 80..463 : h0 = relu(nf@Wn+bn) and sp = h0@Wa[:H]+ba
// blocks 464..475: invdeg[j] = 1/max(sum_i adj[i][j], 1)
__global__ __launch_bounds__(256) void k_prep(
                       const float* __restrict__ adj,
                       const float* __restrict__ We, const float* __restrict__ Wa,
                       unsigned short* __restrict__ WeT, unsigned short* __restrict__ Wa2T,
                       const float* __restrict__ nf, const float* __restrict__ Wn,
                       const float* __restrict__ bn, const float* __restrict__ ba,
                       float* __restrict__ h, float* __restrict__ sp,
                       float* __restrict__ invdeg) {
    const int b = blockIdx.x, tid = threadIdx.x;
    if (b < 80) {
        int g = b * 256 + tid;
        if (g < 128 * 32) {
            int c = g >> 5, f = g & 31;
            WeT[g] = to_bf16u(We[f * 128 + c]);
        } else {
            int g2 = g - 128 * 32;
            int c = g2 >> 7, k = g2 & 127;
            Wa2T[g2] = to_bf16u(Wa[(128 + k) * 128 + c]);
        }
    } else if (b < 464) {
        __shared__ float nf_l[2][64];
        __shared__ float h_l[2][128];
        int row = tid >> 7, t = tid & 127;
        int i = (b - 80) * 2 + row;
        if (t < 64) nf_l[row][t] = nf[i * 64 + t];
        __syncthreads();
        float acc = bn[t];
#pragma unroll 8
        for (int f = 0; f < 64; ++f) acc += nf_l[row][f] * Wn[f * 128 + t];
        acc = fmaxf(acc, 0.f);
        h[i * 128 + t] = acc;
        h_l[row][t] = acc;
        __syncthreads();
        float spv = ba[t];
#pragma unroll 8
        for (int f = 0; f < 128; ++f) spv += h_l[row][f] * Wa[f * 128 + t];
        sp[i * 128 + t] = spv;
    } else {
        __shared__ float dsum[4][64];
        int d = b - 464;
        int q = tid >> 6, jj = tid & 63;
        int j = d * 64 + jj;
        float s = 0.f;
        for (int i = q * 192; i < q * 192 + 192; ++i)
            s += adj[(size_t)i * NN + j];
        dsum[q][jj] = s;
        __syncthreads();
        if (tid < 64) {
            float tot = dsum[0][tid] + dsum[1][tid] + dsum[2][tid] + dsum[3][tid];
            invdeg[d * 64 + tid] = 1.0f / fmaxf(tot, 1.0f);
        }
    }
}

// ---------------------------------------------------------------- eproj build
// Block = sender i. 8 waves in 2x4 (wr = 16-row half of the 32-j chunk,
// wc = 32-col quarter). 24 chunks, dbuf e_lds + o_lds, 1 barrier/chunk.
// eproj[i*768+j][k] = (relu(ef[i][j]@We + be)) @ Wa2, bf16.
__global__ __launch_bounds__(512) void k_build(
    const float* __restrict__ ef, const unsigned short* __restrict__ WeT,
    const unsigned short* __restrict__ Wa2T, const float* __restrict__ be,
    unsigned short* __restrict__ eproj) {
    __shared__ __align__(16) unsigned short e_lds[2][32 * 128];  // 16KB dbuf
    __shared__ __align__(16) unsigned short o_lds[2][32 * 128];  // 16KB dbuf
    const int tid  = threadIdx.x;
    const int lane = tid & 63;
    const int wv   = tid >> 6;
    const int wr   = wv >> 2;
    const int wc   = wv & 3;
    const int lg   = lane >> 4;
    const int lr   = lane & 15;
    const size_t gbase = (size_t)blockIdx.x * NN;

    // B-frags in regs
    bf16x8 bwe[2];
    bf16x8 bwa[2][4];
    float bereg[2];
#pragma unroll
    for (int t = 0; t < 2; ++t) {
        const int col = 32 * wc + 16 * t + lr;
        bwe[t] = *reinterpret_cast<const bf16x8*>(WeT + col * 32 + 8 * lg);
        bereg[t] = be[col];
#pragma unroll
        for (int s = 0; s < 4; ++s)
            bwa[t][s] = *reinterpret_cast<const bf16x8*>(Wa2T + col * 128 + 32 * s + 8 * lg);
    }

    // A-frag direct from ef: rows contiguous 128B, wave = 2KB coalesced
    auto load_a = [&](int n, bf16x8& x) {
        const float* p = ef + (gbase + 32 * n + 16 * wr + lr) * 32 + 8 * lg;
        float4 f0 = *reinterpret_cast<const float4*>(p);
        float4 f1 = *reinterpret_cast<const float4*>(p + 4);
        x[0] = (__bf16)f0.x; x[1] = (__bf16)f0.y; x[2] = (__bf16)f0.z; x[3] = (__bf16)f0.w;
        x[4] = (__bf16)f1.x; x[5] = (__bf16)f1.y; x[6] = (__bf16)f1.z; x[7] = (__bf16)f1.w;
    };
    // GEMM1: E(16 rows x 32 cols per wave) = relu(EF @ We + be) -> swizzled
    auto gemm1 = [&](bf16x8 a, int buf) {
#pragma unroll
        for (int t = 0; t < 2; ++t) {
            const int col = 32 * wc + 16 * t + lr;
            f32x4 c;
            c[0] = bereg[t]; c[1] = bereg[t]; c[2] = bereg[t]; c[3] = bereg[t];
            f32x4 C1 = __builtin_amdgcn_mfma_f32_16x16x32_bf16(a, bwe[t], c, 0, 0, 0);
#pragma unroll
            for (int r = 0; r < 4; ++r) {
                int row = 16 * wr + 4 * lg + r;
                int idx = (row * 128 + col) ^ ((row & 7) << 3);
                e_lds[buf][idx] = to_bf16u(fmaxf(C1[r], 0.f));
            }
        }
    };

    bf16x8 cA, pA;
    load_a(0, cA);
    gemm1(cA, 0);
    load_a(1, cA);
    __syncthreads();   // E[0] ready

    for (int n = 0; n < 24; ++n) {
        const int b = n & 1;
        if (n + 2 < 24) load_a(n + 2, pA);
        if (n + 1 < 24) gemm1(cA, b ^ 1);

        // GEMM2(n): e_lds[b] -> o_lds[b] (swizzled bf16)
        bf16x8 ae[4];
        const int erow = 16 * wr + lr;
#pragma unroll
        for (int s = 0; s < 4; ++s) {
            int idx = (erow * 128 + 32 * s + 8 * lg) ^ ((erow & 7) << 3);
            ae[s] = *reinterpret_cast<const bf16x8*>(&e_lds[b][idx]);
        }
#pragma unroll
        for (int t = 0; t < 2; ++t) {
            f32x4 acc;
            acc[0] = 0.f; acc[1] = 0.f; acc[2] = 0.f; acc[3] = 0.f;
#pragma unroll
            for (int s = 0; s < 4; ++s)
                acc = __builtin_amdgcn_mfma_f32_16x16x32_bf16(ae[s], bwa[t][s], acc, 0, 0, 0);
            const int col = 32 * wc + 16 * t + lr;
#pragma unroll
            for (int r = 0; r < 4; ++r) {
                int row = 16 * wr + 4 * lg + r;
                int idx = (row * 128 + col) ^ ((row & 7) << 3);
                o_lds[b][idx] = to_bf16u(acc[r]);
            }
        }
        __syncthreads();   // o_lds[b] complete; e_lds[b^1] complete

        // coalesced store: thread tid -> row=tid>>4, group a=tid&15 (16B)
        {
            const int row = tid >> 4, a = tid & 15;
            int idx = row * 128 + 8 * (a ^ (row & 7));
            f32x4 v = *reinterpret_cast<const f32x4*>(&o_lds[b][idx]);
            *reinterpret_cast<f32x4*>(eproj + (gbase + 32 * n + row) * 128 + 8 * a) = v;
        }

        if (n + 2 < 24) cA = pA;
    }
}

// ---------------------------------------------------------------- streaming round
// Block b: jt = b>>4 (16 receivers j0=jt*16), seg = b&15 (48 senders).
// acc[j][k] += relu(sp[i][k] + eproj[i*768+j][k]) * adj[i][j].
__global__ __launch_bounds__(256) void k_round(
    const unsigned short* __restrict__ eproj, const float* __restrict__ adj,
    const float* __restrict__ sp, float* __restrict__ aggp) {
    const int tid = threadIdx.x;
    const int jt  = blockIdx.x >> 4;
    const int seg = blockIdx.x & 15;
    const int j0  = jt * 16;
    const int i0  = seg * 48;
    const int jj  = tid >> 4;
    const int kb  = (tid & 15) * 8;

    const size_t estep = (size_t)NN * 128;
    const unsigned short* ep = eproj + ((size_t)i0 * NN + j0 + jj) * 128 + kb;
    const float* ap = adj + (size_t)i0 * NN + j0 + jj;
    const float* spp = sp + (size_t)i0 * 128 + kb;

    float acc[8] = {0.f, 0.f, 0.f, 0.f, 0.f, 0.f, 0.f, 0.f};

    bf16x8 v = *reinterpret_cast<const bf16x8*>(ep);
    float av = *ap;
    float4 s0 = *reinterpret_cast<const float4*>(spp);
    float4 s1 = *reinterpret_cast<const float4*>(spp + 4);

    for (int m = 0; m < 48; ++m) {
        bf16x8 vn = v; float avn = av; float4 s0n = s0, s1n = s1;
        if (m < 47) {
            vn = *reinterpret_cast<const bf16x8*>(ep + estep);
            avn = ap[NN];
            s0n = *reinterpret_cast<const float4*>(spp + 128);
            s1n = *reinterpret_cast<const float4*>(spp + 132);
        }
        acc[0] += fmaxf(s0.x + (float)v[0], 0.f) * av;
        acc[1] += fmaxf(s0.y + (float)v[1], 0.f) * av;
        acc[2] += fmaxf(s0.z + (float)v[2], 0.f) * av;
        acc[3] += fmaxf(s0.w + (float)v[3], 0.f) * av;
        acc[4] += fmaxf(s1.x + (float)v[4], 0.f) * av;
        acc[5] += fmaxf(s1.y + (float)v[5], 0.f) * av;
        acc[6] += fmaxf(s1.z + (float)v[6], 0.f) * av;
        acc[7] += fmaxf(s1.w + (float)v[7], 0.f) * av;
        ep += estep; ap += NN; spp += 128;
        v = vn; av = avn; s0 = s0n; s1 = s1n;
    }

    float* dst = aggp + ((size_t)(j0 + jj) * 16 + seg) * 128 + kb;
    float4 o0, o1;
    o0.x = acc[0]; o0.y = acc[1]; o0.z = acc[2]; o0.w = acc[3];
    o1.x = acc[4]; o1.y = acc[5]; o1.z = acc[6]; o1.w = acc[7];
    *reinterpret_cast<float4*>(dst) = o0;
    *reinterpret_cast<float4*>(dst + 4) = o1;
}

// ---------------------------------------------------------------- update (reduce partials + GEMM)
template <int LAST>
__global__ __launch_bounds__(256) void k_upd(
                      const float* __restrict__ h_in, const float* __restrict__ aggp,
                      const float* __restrict__ invdeg,
                      const float* __restrict__ Wu, const float* __restrict__ bu,
                      const float* __restrict__ Wa, const float* __restrict__ ba,
                      float* __restrict__ h_out, float* __restrict__ sp,
                      float* __restrict__ out) {
    __shared__ float buf[2][256];
    __shared__ float hn[2][128];
    const int tid = threadIdx.x;
    const int row = tid >> 7, t = tid & 127;
    const int j = blockIdx.x * 2 + row;
    float s = 0.f;
#pragma unroll
    for (int seg = 0; seg < 16; ++seg)
        s += aggp[((size_t)j * 16 + seg) * 128 + t];
    buf[row][t] = h_in[j * 128 + t];
    buf[row][128 + t] = s * invdeg[j];
    __syncthreads();
    float acc = bu[t];
#pragma unroll 8
    for (int f = 0; f < 256; ++f) acc += buf[row][f] * Wu[f * 128 + t];
    acc = fmaxf(acc, 0.f);
    if (LAST) {
        out[j * 128 + t] = acc;
    } else {
        h_out[j * 128 + t] = acc;
        hn[row][t] = acc;
        __syncthreads();
        float spv = ba[t];
#pragma unroll 8
        for (int f = 0; f < 128; ++f) spv += hn[row][f] * Wa[f * 128 + t];
        sp[j * 128 + t] = spv;
    }
}

// ---------------------------------------------------------------- graph embedding
__global__ __launch_bounds__(64) void k_gemb(const float* __restrict__ out_h, float* __restrict__ out) {
    int c = blockIdx.x, l = threadIdx.x;
    float acc = 0.f;
    for (int i = l; i < NN; i += 64) acc += out_h[(size_t)i * 128 + c];
#pragma unroll
    for (int off = 32; off; off >>= 1) acc += __shfl_down(acc, off);
    if (l == 0) out[NN * 128 + c] = acc * (1.0f / 768.0f);
}

extern "C" void kernel_launch(void* const* d_in, const int* in_sizes, int n_in,
                              void* d_out, int out_size, void* d_ws, size_t ws_size,
                              hipStream_t stream) {
    const float* nf  = (const float*)d_in[0];
    const float* ef  = (const float*)d_in[1];
    const float* adj = (const float*)d_in[2];
    const float* Wn  = (const float*)d_in[3];
    const float* bn  = (const float*)d_in[4];
    const float* We  = (const float*)d_in[5];
    const float* be  = (const float*)d_in[6];
    const float* Wa  = (const float*)d_in[7];
    const float* ba  = (const float*)d_in[8];
    const float* Wu  = (const float*)d_in[9];
    const float* bu  = (const float*)d_in[10];
    float* out = (float*)d_out;

    // ws layout (floats): h | sp | invdeg | aggp | WeT(us) | Wa2T(us) | eproj(us)
    float* h_buf  = (float*)d_ws;
    float* sp     = h_buf + NN * 128;
    float* invdeg = sp + NN * 128;
    float* aggp   = invdeg + NN;
    unsigned short* WeT   = (unsigned short*)(aggp + (size_t)NN * 16 * 128);
    unsigned short* Wa2T  = WeT + 128 * 32;
    unsigned short* eproj = Wa2T + 128 * 128;

    k_prep<<<476, 256, 0, stream>>>(adj, We, Wa, WeT, Wa2T, nf, Wn, bn, ba,
                                    h_buf, sp, invdeg);
    k_build<<<NN, 512, 0, stream>>>(ef, WeT, Wa2T, be, eproj);

    k_round<<<48 * 16, 256, 0, stream>>>(eproj, adj, sp, aggp);
    k_upd<0><<<NN / 2, 256, 0, stream>>>(h_buf, aggp, invdeg, Wu, bu, Wa, ba, h_buf, sp, out);
    k_round<<<48 * 16, 256, 0, stream>>>(eproj, adj, sp, aggp);
    k_upd<1><<<NN / 2, 256, 0, stream>>>(h_buf, aggp, invdeg, Wu, bu, Wa, ba, h_buf, sp, out);

    k_gemb<<<128, 64, 0, stream>>>(out, out);
}

// Round 19
// 142.584 us; speedup vs baseline: 1.5379x; 1.0111x over previous
//
#include <hip/hip_runtime.h>
#include <hip/hip_bf16.h>

// GraphSAGE fused kernels for MI355X (gfx950).
// N=768, NODE_IN=64, EDGE_IN=32, H=128, ROUNDS=2.
//
// Round 19: k_build with BOTH GEMMs operand-swapped (out^T = mfma(W, X)):
// lane's C-fragment becomes 4 consecutive H-cols for a fixed j-row, so all
// LDS writes are packed b64 instead of scalar u16 (21 -> 9 LDS ops per
// chunk-lane; R18 was LDS-op-bound at MfmaUtil 12%). e_lds/o_lds stay
// row-major [j][H] swizzled; store epilogue identical to R18 (verified
// coalesced). Pipeline/barriers/k_prep/k_round/k_upd unchanged.

typedef __bf16 bf16x8 __attribute__((ext_vector_type(8)));
typedef float f32x4 __attribute__((ext_vector_type(4)));

#define NN 768

static __device__ __forceinline__ unsigned short to_bf16u(float x) {
    return __builtin_bit_cast(unsigned short, (__bf16)x);
}

// ---------------------------------------------------------------- fused prep
// blocks 0..79   : weight transposes We->WeT, Wa[H:]->Wa2T (bf16 k-minor)
// blocks 80..463 : h0 = relu(nf@Wn+bn) and sp = h0@Wa[:H]+ba
// blocks 464..475: invdeg[j] = 1/max(sum_i adj[i][j], 1)
__global__ __launch_bounds__(256) void k_prep(
                       const float* __restrict__ adj,
                       const float* __restrict__ We, const float* __restrict__ Wa,
                       unsigned short* __restrict__ WeT, unsigned short* __restrict__ Wa2T,
                       const float* __restrict__ nf, const float* __restrict__ Wn,
                       const float* __restrict__ bn, const float* __restrict__ ba,
                       float* __restrict__ h, float* __restrict__ sp,
                       float* __restrict__ invdeg) {
    const int b = blockIdx.x, tid = threadIdx.x;
    if (b < 80) {
        int g = b * 256 + tid;
        if (g < 128 * 32) {
            int c = g >> 5, f = g & 31;
            WeT[g] = to_bf16u(We[f * 128 + c]);
        } else {
            int g2 = g - 128 * 32;
            int c = g2 >> 7, k = g2 & 127;
            Wa2T[g2] = to_bf16u(Wa[(128 + k) * 128 + c]);
        }
    } else if (b < 464) {
        __shared__ float nf_l[2][64];
        __shared__ float h_l[2][128];
        int row = tid >> 7, t = tid & 127;
        int i = (b - 80) * 2 + row;
        if (t < 64) nf_l[row][t] = nf[i * 64 + t];
        __syncthreads();
        float acc = bn[t];
#pragma unroll 8
        for (int f = 0; f < 64; ++f) acc += nf_l[row][f] * Wn[f * 128 + t];
        acc = fmaxf(acc, 0.f);
        h[i * 128 + t] = acc;
        h_l[row][t] = acc;
        __syncthreads();
        float spv = ba[t];
#pragma unroll 8
        for (int f = 0; f < 128; ++f) spv += h_l[row][f] * Wa[f * 128 + t];
        sp[i * 128 + t] = spv;
    } else {
        __shared__ float dsum[4][64];
        int d = b - 464;
        int q = tid >> 6, jj = tid & 63;
        int j = d * 64 + jj;
        float s = 0.f;
        for (int i = q * 192; i < q * 192 + 192; ++i)
            s += adj[(size_t)i * NN + j];
        dsum[q][jj] = s;
        __syncthreads();
        if (tid < 64) {
            float tot = dsum[0][tid] + dsum[1][tid] + dsum[2][tid] + dsum[3][tid];
            invdeg[d * 64 + tid] = 1.0f / fmaxf(tot, 1.0f);
        }
    }
}

// ---------------------------------------------------------------- eproj build
// Block = sender i. 8 waves in 2x4 (wr = 16-j half of the 32-j chunk,
// wc = 32-col quarter). 24 chunks, dbuf e_lds/o_lds, 1 barrier/chunk.
// Both GEMMs swapped: D = mfma(W, X) = out^T, so lane holds 4 consecutive
// H-cols for fixed j -> packed b64 LDS writes.
__global__ __launch_bounds__(512) void k_build(
    const float* __restrict__ ef, const unsigned short* __restrict__ WeT,
    const unsigned short* __restrict__ Wa2T, const float* __restrict__ be,
    unsigned short* __restrict__ eproj) {
    __shared__ __align__(16) unsigned short e_lds[2][32 * 128];  // 16KB dbuf, [j][H]
    __shared__ __align__(16) unsigned short o_lds[2][32 * 128];  // 16KB dbuf, [j][K]
    const int tid  = threadIdx.x;
    const int lane = tid & 63;
    const int wv   = tid >> 6;
    const int wr   = wv >> 2;
    const int wc   = wv & 3;
    const int lg   = lane >> 4;
    const int lr   = lane & 15;
    const size_t gbase = (size_t)blockIdx.x * NN;

    // weight A-operand frags + be C-init vectors
    bf16x8 bwe[2];
    bf16x8 bwa[2][4];
    f32x4 bev[2];
#pragma unroll
    for (int t = 0; t < 2; ++t) {
        const int col = 32 * wc + 16 * t + lr;
        bwe[t] = *reinterpret_cast<const bf16x8*>(WeT + col * 32 + 8 * lg);
        bev[t] = *reinterpret_cast<const f32x4*>(be + 32 * wc + 16 * t + 4 * lg);
#pragma unroll
        for (int s = 0; s < 4; ++s)
            bwa[t][s] = *reinterpret_cast<const bf16x8*>(Wa2T + col * 128 + 32 * s + 8 * lg);
    }

    // ef B-operand frag: row j = 32n+16wr+lr, contiguous 128B rows
    auto load_a = [&](int n, bf16x8& x) {
        const float* p = ef + (gbase + 32 * n + 16 * wr + lr) * 32 + 8 * lg;
        float4 f0 = *reinterpret_cast<const float4*>(p);
        float4 f1 = *reinterpret_cast<const float4*>(p + 4);
        x[0] = (__bf16)f0.x; x[1] = (__bf16)f0.y; x[2] = (__bf16)f0.z; x[3] = (__bf16)f0.w;
        x[4] = (__bf16)f1.x; x[5] = (__bf16)f1.y; x[6] = (__bf16)f1.z; x[7] = (__bf16)f1.w;
    };
    // GEMM1 swapped: D = We^T @ EF^T + be -> lane holds E[j=16wr+lr][4 consecutive H]
    auto gemm1 = [&](bf16x8 aef, int buf) {
        const int row = 16 * wr + lr;
#pragma unroll
        for (int t = 0; t < 2; ++t) {
            f32x4 D = __builtin_amdgcn_mfma_f32_16x16x32_bf16(bwe[t], aef, bev[t], 0, 0, 0);
            ushort4 pk;
            pk.x = to_bf16u(fmaxf(D[0], 0.f));
            pk.y = to_bf16u(fmaxf(D[1], 0.f));
            pk.z = to_bf16u(fmaxf(D[2], 0.f));
            pk.w = to_bf16u(fmaxf(D[3], 0.f));
            int cb = 32 * wc + 16 * t + 4 * lg;
            int idx = (row * 128 + cb) ^ ((row & 7) << 3);
            *reinterpret_cast<ushort4*>(&e_lds[buf][idx]) = pk;
        }
    };

    bf16x8 cA, pA;
    load_a(0, cA);
    gemm1(cA, 0);
    load_a(1, cA);
    __syncthreads();   // E[0] ready

    for (int n = 0; n < 24; ++n) {
        const int b = n & 1;
        if (n + 2 < 24) load_a(n + 2, pA);
        if (n + 1 < 24) gemm1(cA, b ^ 1);

        // GEMM2 swapped: D = Wa2^T @ E^T -> lane holds out[j=16wr+lr][4 consec K]
        const int row = 16 * wr + lr;
        bf16x8 eb[4];
#pragma unroll
        for (int s = 0; s < 4; ++s) {
            int idx = (row * 128 + 32 * s + 8 * lg) ^ ((row & 7) << 3);
            eb[s] = *reinterpret_cast<const bf16x8*>(&e_lds[b][idx]);
        }
#pragma unroll
        for (int t = 0; t < 2; ++t) {
            f32x4 D;
            D[0] = 0.f; D[1] = 0.f; D[2] = 0.f; D[3] = 0.f;
#pragma unroll
            for (int s = 0; s < 4; ++s)
                D = __builtin_amdgcn_mfma_f32_16x16x32_bf16(bwa[t][s], eb[s], D, 0, 0, 0);
            ushort4 pk;
            pk.x = to_bf16u(D[0]); pk.y = to_bf16u(D[1]);
            pk.z = to_bf16u(D[2]); pk.w = to_bf16u(D[3]);
            int cb = 32 * wc + 16 * t + 4 * lg;
            int idx = (row * 128 + cb) ^ ((row & 7) << 3);
            *reinterpret_cast<ushort4*>(&o_lds[b][idx]) = pk;
        }
        __syncthreads();   // o_lds[b] complete; e_lds[b^1] complete

        // coalesced store: thread tid -> row=tid>>4 (j), group a=tid&15 (16B)
        {
            const int srow = tid >> 4, a = tid & 15;
            int idx = srow * 128 + 8 * (a ^ (srow & 7));
            f32x4 v = *reinterpret_cast<const f32x4*>(&o_lds[b][idx]);
            *reinterpret_cast<f32x4*>(eproj + (gbase + 32 * n + srow) * 128 + 8 * a) = v;
        }

        if (n + 2 < 24) cA = pA;
    }
}

// ---------------------------------------------------------------- streaming round
// Block b: jt = b>>4 (16 receivers j0=jt*16), seg = b&15 (48 senders).
// acc[j][k] += relu(sp[i][k] + eproj[i*768+j][k]) * adj[i][j].
__global__ __launch_bounds__(256) void k_round(
    const unsigned short* __restrict__ eproj, const float* __restrict__ adj,
    const float* __restrict__ sp, float* __restrict__ aggp) {
    const int tid = threadIdx.x;
    const int jt  = blockIdx.x >> 4;
    const int seg = blockIdx.x & 15;
    const int j0  = jt * 16;
    const int i0  = seg * 48;
    const int jj  = tid >> 4;
    const int kb  = (tid & 15) * 8;

    const size_t estep = (size_t)NN * 128;
    const unsigned short* ep = eproj + ((size_t)i0 * NN + j0 + jj) * 128 + kb;
    const float* ap = adj + (size_t)i0 * NN + j0 + jj;
    const float* spp = sp + (size_t)i0 * 128 + kb;

    float acc[8] = {0.f, 0.f, 0.f, 0.f, 0.f, 0.f, 0.f, 0.f};

    bf16x8 v = *reinterpret_cast<const bf16x8*>(ep);
    float av = *ap;
    float4 s0 = *reinterpret_cast<const float4*>(spp);
    float4 s1 = *reinterpret_cast<const float4*>(spp + 4);

    for (int m = 0; m < 48; ++m) {
        bf16x8 vn = v; float avn = av; float4 s0n = s0, s1n = s1;
        if (m < 47) {
            vn = *reinterpret_cast<const bf16x8*>(ep + estep);
            avn = ap[NN];
            s0n = *reinterpret_cast<const float4*>(spp + 128);
            s1n = *reinterpret_cast<const float4*>(spp + 132);
        }
        acc[0] += fmaxf(s0.x + (float)v[0], 0.f) * av;
        acc[1] += fmaxf(s0.y + (float)v[1], 0.f) * av;
        acc[2] += fmaxf(s0.z + (float)v[2], 0.f) * av;
        acc[3] += fmaxf(s0.w + (float)v[3], 0.f) * av;
        acc[4] += fmaxf(s1.x + (float)v[4], 0.f) * av;
        acc[5] += fmaxf(s1.y + (float)v[5], 0.f) * av;
        acc[6] += fmaxf(s1.z + (float)v[6], 0.f) * av;
        acc[7] += fmaxf(s1.w + (float)v[7], 0.f) * av;
        ep += estep; ap += NN; spp += 128;
        v = vn; av = avn; s0 = s0n; s1 = s1n;
    }

    float* dst = aggp + ((size_t)(j0 + jj) * 16 + seg) * 128 + kb;
    float4 o0, o1;
    o0.x = acc[0]; o0.y = acc[1]; o0.z = acc[2]; o0.w = acc[3];
    o1.x = acc[4]; o1.y = acc[5]; o1.z = acc[6]; o1.w = acc[7];
    *reinterpret_cast<float4*>(dst) = o0;
    *reinterpret_cast<float4*>(dst + 4) = o1;
}

// ---------------------------------------------------------------- update (reduce partials + GEMM)
template <int LAST>
__global__ __launch_bounds__(256) void k_upd(
                      const float* __restrict__ h_in, const float* __restrict__ aggp,
                      const float* __restrict__ invdeg,
                      const float* __restrict__ Wu, const float* __restrict__ bu,
                      const float* __restrict__ Wa, const float* __restrict__ ba,
                      float* __restrict__ h_out, float* __restrict__ sp,
                      float* __restrict__ out) {
    __shared__ float buf[2][256];
    __shared__ float hn[2][128];
    const int tid = threadIdx.x;
    const int row = tid >> 7, t = tid & 127;
    const int j = blockIdx.x * 2 + row;
    float s = 0.f;
#pragma unroll
    for (int seg = 0; seg < 16; ++seg)
        s += aggp[((size_t)j * 16 + seg) * 128 + t];
    buf[row][t] = h_in[j * 128 + t];
    buf[row][128 + t] = s * invdeg[j];
    __syncthreads();
    float acc = bu[t];
#pragma unroll 8
    for (int f = 0; f < 256; ++f) acc += buf[row][f] * Wu[f * 128 + t];
    acc = fmaxf(acc, 0.f);
    if (LAST) {
        out[j * 128 + t] = acc;
    } else {
        h_out[j * 128 + t] = acc;
        hn[row][t] = acc;
        __syncthreads();
        float spv = ba[t];
#pragma unroll 8
        for (int f = 0; f < 128; ++f) spv += hn[row][f] * Wa[f * 128 + t];
        sp[j * 128 + t] = spv;
    }
}

// ---------------------------------------------------------------- graph embedding
__global__ __launch_bounds__(64) void k_gemb(const float* __restrict__ out_h, float* __restrict__ out) {
    int c = blockIdx.x, l = threadIdx.x;
    float acc = 0.f;
    for (int i = l; i < NN; i += 64) acc += out_h[(size_t)i * 128 + c];
#pragma unroll
    for (int off = 32; off; off >>= 1) acc += __shfl_down(acc, off);
    if (l == 0) out[NN * 128 + c] = acc * (1.0f / 768.0f);
}

extern "C" void kernel_launch(void* const* d_in, const int* in_sizes, int n_in,
                              void* d_out, int out_size, void* d_ws, size_t ws_size,
                              hipStream_t stream) {
    const float* nf  = (const float*)d_in[0];
    const float* ef  = (const float*)d_in[1];
    const float* adj = (const float*)d_in[2];
    const float* Wn  = (const float*)d_in[3];
    const float* bn  = (const float*)d_in[4];
    const float* We  = (const float*)d_in[5];
    const float* be  = (const float*)d_in[6];
    const float* Wa  = (const float*)d_in[7];
    const float* ba  = (const float*)d_in[8];
    const float* Wu  = (const float*)d_in[9];
    const float* bu  = (const float*)d_in[10];
    float* out = (float*)d_out;

    // ws layout (floats): h | sp | invdeg | aggp | WeT(us) | Wa2T(us) | eproj(us)
    float* h_buf  = (float*)d_ws;
    float* sp     = h_buf + NN * 128;
    float* invdeg = sp + NN * 128;
    float* aggp   = invdeg + NN;
    unsigned short* WeT   = (unsigned short*)(aggp + (size_t)NN * 16 * 128);
    unsigned short* Wa2T  = WeT + 128 * 32;
    unsigned short* eproj = Wa2T + 128 * 128;

    k_prep<<<476, 256, 0, stream>>>(adj, We, Wa, WeT, Wa2T, nf, Wn, bn, ba,
                                    h_buf, sp, invdeg);
    k_build<<<NN, 512, 0, stream>>>(ef, WeT, Wa2T, be, eproj);

    k_round<<<48 * 16, 256, 0, stream>>>(eproj, adj, sp, aggp);
    k_upd<0><<<NN / 2, 256, 0, stream>>>(h_buf, aggp, invdeg, Wu, bu, Wa, ba, h_buf, sp, out);
    k_round<<<48 * 16, 256, 0, stream>>>(eproj, adj, sp, aggp);
    k_upd<1><<<NN / 2, 256, 0, stream>>>(h_buf, aggp, invdeg, Wu, bu, Wa, ba, h_buf, sp, out);

    k_gemb<<<128, 64, 0, stream>>>(out, out);
}